// Round 1
// baseline (1895.545 us; speedup 1.0000x reference)
//
#include <hip/hip_runtime.h>
#include <math.h>

#define B_ 2
#define S_ 2048
#define E_ 1024
#define H_ 16
#define D_ 64

// ---------------- C[M][N] = A[M][K] @ W[K][N] + bias[N], fp32 ----------------
__global__ __launch_bounds__(256)
void gemm_bias_f32(const float* __restrict__ A, const float* __restrict__ W,
                   const float* __restrict__ bias, float* __restrict__ C,
                   int M, int N, int K)
{
    constexpr int BK = 16;
    __shared__ float As[BK][128 + 4];
    __shared__ float Bs[BK][128 + 4];
    const int tid = threadIdx.x;
    const int n0 = blockIdx.x * 128;
    const int m0 = blockIdx.y * 128;
    const int tx = tid & 15;
    const int ty = tid >> 4;

    float acc[8][8];
#pragma unroll
    for (int i = 0; i < 8; ++i)
#pragma unroll
        for (int j = 0; j < 8; ++j) acc[i][j] = 0.f;

    const int am = tid >> 1;
    const int ak = (tid & 1) * 8;
    const int bk = tid >> 4;
    const int bn = (tid & 15) * 8;

    for (int k0 = 0; k0 < K; k0 += BK) {
        const float4 a0 = *reinterpret_cast<const float4*>(&A[(size_t)(m0 + am) * K + k0 + ak]);
        const float4 a1 = *reinterpret_cast<const float4*>(&A[(size_t)(m0 + am) * K + k0 + ak + 4]);
        const float4 b0 = *reinterpret_cast<const float4*>(&W[(size_t)(k0 + bk) * N + n0 + bn]);
        const float4 b1 = *reinterpret_cast<const float4*>(&W[(size_t)(k0 + bk) * N + n0 + bn + 4]);
        As[ak + 0][am] = a0.x; As[ak + 1][am] = a0.y; As[ak + 2][am] = a0.z; As[ak + 3][am] = a0.w;
        As[ak + 4][am] = a1.x; As[ak + 5][am] = a1.y; As[ak + 6][am] = a1.z; As[ak + 7][am] = a1.w;
        *reinterpret_cast<float4*>(&Bs[bk][bn])     = b0;
        *reinterpret_cast<float4*>(&Bs[bk][bn + 4]) = b1;
        __syncthreads();
#pragma unroll
        for (int k = 0; k < BK; ++k) {
            float a[8], b[8];
            *reinterpret_cast<float4*>(&a[0]) = *reinterpret_cast<const float4*>(&As[k][ty * 8]);
            *reinterpret_cast<float4*>(&a[4]) = *reinterpret_cast<const float4*>(&As[k][ty * 8 + 4]);
            *reinterpret_cast<float4*>(&b[0]) = *reinterpret_cast<const float4*>(&Bs[k][tx * 8]);
            *reinterpret_cast<float4*>(&b[4]) = *reinterpret_cast<const float4*>(&Bs[k][tx * 8 + 4]);
#pragma unroll
            for (int i = 0; i < 8; ++i)
#pragma unroll
                for (int j = 0; j < 8; ++j)
                    acc[i][j] = fmaf(a[i], b[j], acc[i][j]);
        }
        __syncthreads();
    }

    float bv[8];
    *reinterpret_cast<float4*>(&bv[0]) = *reinterpret_cast<const float4*>(&bias[n0 + tx * 8]);
    *reinterpret_cast<float4*>(&bv[4]) = *reinterpret_cast<const float4*>(&bias[n0 + tx * 8 + 4]);
#pragma unroll
    for (int i = 0; i < 8; ++i) {
        float o[8];
#pragma unroll
        for (int j = 0; j < 8; ++j) o[j] = acc[i][j] + bv[j];
        float* dst = &C[(size_t)(m0 + ty * 8 + i) * N + n0 + tx * 8];
        *reinterpret_cast<float4*>(dst)     = *reinterpret_cast<const float4*>(&o[0]);
        *reinterpret_cast<float4*>(dst + 4) = *reinterpret_cast<const float4*>(&o[4]);
    }
}

// ---------------- fused flash attention per (b,h), fp32 ----------------
// Head view: Qh/Kh/Vh are contiguous [S_][D_] at offset b*S*E + h*S*D.
// Output written transposed into XH[b][s2][h*D + d].
__global__ __launch_bounds__(256)
void attn_f32(const float* __restrict__ Q, const float* __restrict__ K,
              const float* __restrict__ V, float* __restrict__ O)
{
    __shared__ float Ks[64][D_ + 4];
    __shared__ float Vs[64][D_ + 4];
    __shared__ float Ss[64][D_ + 1];   // Q staging, then scores
    const int tid = threadIdx.x;
    const int qb = blockIdx.x;         // 0..31 q-tile
    const int bh = blockIdx.y;         // 0..31
    const int b  = bh >> 4;
    const int h  = bh & 15;
    const size_t hoff = (size_t)b * S_ * E_ + (size_t)h * S_ * D_;
    const float* Qh = Q + hoff;
    const float* Kh = K + hoff;
    const float* Vh = V + hoff;

    const int i  = tid & 63;   // q-row within tile (= lane)
    const int dg = tid >> 6;   // wave id = d-group / score col-group
    const int r  = tid >> 2;   // staging row
    const int c  = (tid & 3) * 16;

    // stage Q tile into Ss (coalesced), then pull own row into registers
    {
        const float* src = &Qh[(size_t)(qb * 64 + r) * D_ + c];
#pragma unroll
        for (int u = 0; u < 4; ++u) {
            float4 v = *reinterpret_cast<const float4*>(src + 4 * u);
            Ss[r][c + 4 * u + 0] = v.x;
            Ss[r][c + 4 * u + 1] = v.y;
            Ss[r][c + 4 * u + 2] = v.z;
            Ss[r][c + 4 * u + 3] = v.w;
        }
    }
    __syncthreads();
    float q[64];
#pragma unroll
    for (int d = 0; d < 64; ++d) q[d] = Ss[i][d] * 0.125f;  // fold 1/sqrt(D)

    float m = -1e30f, l = 0.f;
    float acc[16];
#pragma unroll
    for (int j = 0; j < 16; ++j) acc[j] = 0.f;

    for (int kt = 0; kt < S_ / 64; ++kt) {
        __syncthreads();   // protect Ks/Vs/Ss from previous iteration readers
        {
            const float* ksrc = &Kh[(size_t)(kt * 64 + r) * D_ + c];
            const float* vsrc = &Vh[(size_t)(kt * 64 + r) * D_ + c];
#pragma unroll
            for (int u = 0; u < 4; ++u) {
                float4 kv = *reinterpret_cast<const float4*>(ksrc + 4 * u);
                float4 vv = *reinterpret_cast<const float4*>(vsrc + 4 * u);
                Ks[r][c + 4 * u + 0] = kv.x; Ks[r][c + 4 * u + 1] = kv.y;
                Ks[r][c + 4 * u + 2] = kv.z; Ks[r][c + 4 * u + 3] = kv.w;
                Vs[r][c + 4 * u + 0] = vv.x; Vs[r][c + 4 * u + 1] = vv.y;
                Vs[r][c + 4 * u + 2] = vv.z; Vs[r][c + 4 * u + 3] = vv.w;
            }
        }
        __syncthreads();

        // scores s[i][dg*16+j] = q_row_i . k_row  (K rows broadcast across wave)
#pragma unroll
        for (int j = 0; j < 16; ++j) {
            const float* krow = &Ks[dg * 16 + j][0];
            float s = 0.f;
#pragma unroll
            for (int u = 0; u < 16; ++u) {
                float4 kr = *reinterpret_cast<const float4*>(krow + 4 * u);
                s = fmaf(q[4 * u + 0], kr.x, s);
                s = fmaf(q[4 * u + 1], kr.y, s);
                s = fmaf(q[4 * u + 2], kr.z, s);
                s = fmaf(q[4 * u + 3], kr.w, s);
            }
            Ss[i][dg * 16 + j] = s;
        }
        __syncthreads();

        // online softmax update + PV for this thread's (row i, dims dg*16..+15)
        float tmax = -1e30f;
#pragma unroll 8
        for (int k = 0; k < 64; ++k) tmax = fmaxf(tmax, Ss[i][k]);
        const float mnew = fmaxf(m, tmax);
        const float corr = __expf(m - mnew);
        l *= corr;
#pragma unroll
        for (int j = 0; j < 16; ++j) acc[j] *= corr;

        float lsum = 0.f;
#pragma unroll 4
        for (int k = 0; k < 64; ++k) {
            const float p = __expf(Ss[i][k] - mnew);
            lsum += p;
            const float* vrow = &Vs[k][dg * 16];
            float4 v0 = *reinterpret_cast<const float4*>(vrow);
            float4 v1 = *reinterpret_cast<const float4*>(vrow + 4);
            float4 v2 = *reinterpret_cast<const float4*>(vrow + 8);
            float4 v3 = *reinterpret_cast<const float4*>(vrow + 12);
            acc[0]  = fmaf(p, v0.x, acc[0]);
            acc[1]  = fmaf(p, v0.y, acc[1]);
            acc[2]  = fmaf(p, v0.z, acc[2]);
            acc[3]  = fmaf(p, v0.w, acc[3]);
            acc[4]  = fmaf(p, v1.x, acc[4]);
            acc[5]  = fmaf(p, v1.y, acc[5]);
            acc[6]  = fmaf(p, v1.z, acc[6]);
            acc[7]  = fmaf(p, v1.w, acc[7]);
            acc[8]  = fmaf(p, v2.x, acc[8]);
            acc[9]  = fmaf(p, v2.y, acc[9]);
            acc[10] = fmaf(p, v2.z, acc[10]);
            acc[11] = fmaf(p, v2.w, acc[11]);
            acc[12] = fmaf(p, v3.x, acc[12]);
            acc[13] = fmaf(p, v3.y, acc[13]);
            acc[14] = fmaf(p, v3.z, acc[14]);
            acc[15] = fmaf(p, v3.w, acc[15]);
        }
        l += lsum;
        m = mnew;
    }

    const float inv = 1.f / l;
    const int s2 = qb * 64 + i;
    float* dst = O + (size_t)b * S_ * E_ + (size_t)s2 * E_ + (size_t)h * D_ + dg * 16;
#pragma unroll
    for (int u = 0; u < 4; ++u) {
        float4 v = make_float4(acc[4 * u + 0] * inv, acc[4 * u + 1] * inv,
                               acc[4 * u + 2] * inv, acc[4 * u + 3] * inv);
        *reinterpret_cast<float4*>(dst + 4 * u) = v;
    }
}

extern "C" void kernel_launch(void* const* d_in, const int* in_sizes, int n_in,
                              void* d_out, int out_size, void* d_ws, size_t ws_size,
                              hipStream_t stream) {
    (void)in_sizes; (void)n_in; (void)out_size; (void)ws_size;
    const float* x  = (const float*)d_in[0];
    const float* Wq = (const float*)d_in[1];
    const float* bq = (const float*)d_in[2];
    const float* Wk = (const float*)d_in[3];
    const float* bk = (const float*)d_in[4];
    const float* Wv = (const float*)d_in[5];
    const float* bv = (const float*)d_in[6];
    const float* Wo = (const float*)d_in[7];
    const float* bo = (const float*)d_in[8];
    float* out = (float*)d_out;
    float* ws  = (float*)d_ws;

    const size_t NE = (size_t)B_ * S_ * E_;   // 4,194,304 elems per buffer
    float* Qb = ws;
    float* Kb = ws + NE;
    float* Vb = ws + 2 * NE;
    float* XH = ws + 3 * NE;                  // total 64 MiB of ws

    dim3 blk(256);
    dim3 ggrid(E_ / 128, (B_ * S_) / 128);    // (8, 32)
    gemm_bias_f32<<<ggrid, blk, 0, stream>>>(x, Wq, bq, Qb, B_ * S_, E_, E_);
    gemm_bias_f32<<<ggrid, blk, 0, stream>>>(x, Wk, bk, Kb, B_ * S_, E_, E_);
    gemm_bias_f32<<<ggrid, blk, 0, stream>>>(x, Wv, bv, Vb, B_ * S_, E_, E_);

    dim3 agrid(S_ / 64, B_ * H_);             // (32, 32)
    attn_f32<<<agrid, blk, 0, stream>>>(Qb, Kb, Vb, XH);

    gemm_bias_f32<<<ggrid, blk, 0, stream>>>(XH, Wo, bo, out, B_ * S_, E_, E_);
}

// Round 2
// 659.928 us; speedup vs baseline: 2.8724x; 2.8724x over previous
//
#include <hip/hip_runtime.h>
#include <math.h>

#define B_ 2
#define S_ 2048
#define E_ 1024
#define H_ 16
#define D_ 64

typedef __attribute__((ext_vector_type(8))) short short8;
typedef __attribute__((ext_vector_type(4))) float f32x4;
typedef __attribute__((ext_vector_type(4))) unsigned short us4;
typedef __attribute__((ext_vector_type(8))) unsigned short us8;

__device__ __forceinline__ unsigned short f2bf(float f) {
    unsigned int u = __float_as_uint(f);
    u += 0x7FFFu + ((u >> 16) & 1u);
    return (unsigned short)(u >> 16);
}

// ---------------- C = (A @ W + bias) fp32 out ----------------
__global__ __launch_bounds__(256)
void gemm_bias_f32(const float* __restrict__ A, const float* __restrict__ W,
                   const float* __restrict__ bias, float* __restrict__ C,
                   int M, int N, int K)
{
    constexpr int BK = 16;
    __shared__ float As[BK][128 + 4];
    __shared__ float Bs[BK][128 + 4];
    const int tid = threadIdx.x;
    const int n0 = blockIdx.x * 128;
    const int m0 = blockIdx.y * 128;
    const int tx = tid & 15;
    const int ty = tid >> 4;

    float acc[8][8];
#pragma unroll
    for (int i = 0; i < 8; ++i)
#pragma unroll
        for (int j = 0; j < 8; ++j) acc[i][j] = 0.f;

    const int am = tid >> 1;
    const int ak = (tid & 1) * 8;
    const int bk = tid >> 4;
    const int bn = (tid & 15) * 8;

    for (int k0 = 0; k0 < K; k0 += BK) {
        const float4 a0 = *reinterpret_cast<const float4*>(&A[(size_t)(m0 + am) * K + k0 + ak]);
        const float4 a1 = *reinterpret_cast<const float4*>(&A[(size_t)(m0 + am) * K + k0 + ak + 4]);
        const float4 b0 = *reinterpret_cast<const float4*>(&W[(size_t)(k0 + bk) * N + n0 + bn]);
        const float4 b1 = *reinterpret_cast<const float4*>(&W[(size_t)(k0 + bk) * N + n0 + bn + 4]);
        As[ak + 0][am] = a0.x; As[ak + 1][am] = a0.y; As[ak + 2][am] = a0.z; As[ak + 3][am] = a0.w;
        As[ak + 4][am] = a1.x; As[ak + 5][am] = a1.y; As[ak + 6][am] = a1.z; As[ak + 7][am] = a1.w;
        *reinterpret_cast<float4*>(&Bs[bk][bn])     = b0;
        *reinterpret_cast<float4*>(&Bs[bk][bn + 4]) = b1;
        __syncthreads();
#pragma unroll
        for (int k = 0; k < BK; ++k) {
            float a[8], b[8];
            *reinterpret_cast<float4*>(&a[0]) = *reinterpret_cast<const float4*>(&As[k][ty * 8]);
            *reinterpret_cast<float4*>(&a[4]) = *reinterpret_cast<const float4*>(&As[k][ty * 8 + 4]);
            *reinterpret_cast<float4*>(&b[0]) = *reinterpret_cast<const float4*>(&Bs[k][tx * 8]);
            *reinterpret_cast<float4*>(&b[4]) = *reinterpret_cast<const float4*>(&Bs[k][tx * 8 + 4]);
#pragma unroll
            for (int i = 0; i < 8; ++i)
#pragma unroll
                for (int j = 0; j < 8; ++j)
                    acc[i][j] = fmaf(a[i], b[j], acc[i][j]);
        }
        __syncthreads();
    }

    float bv[8];
    *reinterpret_cast<float4*>(&bv[0]) = *reinterpret_cast<const float4*>(&bias[n0 + tx * 8]);
    *reinterpret_cast<float4*>(&bv[4]) = *reinterpret_cast<const float4*>(&bias[n0 + tx * 8 + 4]);
#pragma unroll
    for (int i = 0; i < 8; ++i) {
        float o[8];
#pragma unroll
        for (int j = 0; j < 8; ++j) o[j] = acc[i][j] + bv[j];
        float* dst = &C[(size_t)(m0 + ty * 8 + i) * N + n0 + tx * 8];
        *reinterpret_cast<float4*>(dst)     = *reinterpret_cast<const float4*>(&o[0]);
        *reinterpret_cast<float4*>(dst + 4) = *reinterpret_cast<const float4*>(&o[4]);
    }
}

// ---------------- C = (A @ W + bias)*alpha, bf16 out ----------------
__global__ __launch_bounds__(256)
void gemm_bias_bf16out(const float* __restrict__ A, const float* __restrict__ W,
                       const float* __restrict__ bias, unsigned short* __restrict__ C,
                       int M, int N, int K, float alpha)
{
    constexpr int BK = 16;
    __shared__ float As[BK][128 + 4];
    __shared__ float Bs[BK][128 + 4];
    const int tid = threadIdx.x;
    const int n0 = blockIdx.x * 128;
    const int m0 = blockIdx.y * 128;
    const int tx = tid & 15;
    const int ty = tid >> 4;

    float acc[8][8];
#pragma unroll
    for (int i = 0; i < 8; ++i)
#pragma unroll
        for (int j = 0; j < 8; ++j) acc[i][j] = 0.f;

    const int am = tid >> 1;
    const int ak = (tid & 1) * 8;
    const int bk = tid >> 4;
    const int bn = (tid & 15) * 8;

    for (int k0 = 0; k0 < K; k0 += BK) {
        const float4 a0 = *reinterpret_cast<const float4*>(&A[(size_t)(m0 + am) * K + k0 + ak]);
        const float4 a1 = *reinterpret_cast<const float4*>(&A[(size_t)(m0 + am) * K + k0 + ak + 4]);
        const float4 b0 = *reinterpret_cast<const float4*>(&W[(size_t)(k0 + bk) * N + n0 + bn]);
        const float4 b1 = *reinterpret_cast<const float4*>(&W[(size_t)(k0 + bk) * N + n0 + bn + 4]);
        As[ak + 0][am] = a0.x; As[ak + 1][am] = a0.y; As[ak + 2][am] = a0.z; As[ak + 3][am] = a0.w;
        As[ak + 4][am] = a1.x; As[ak + 5][am] = a1.y; As[ak + 6][am] = a1.z; As[ak + 7][am] = a1.w;
        *reinterpret_cast<float4*>(&Bs[bk][bn])     = b0;
        *reinterpret_cast<float4*>(&Bs[bk][bn + 4]) = b1;
        __syncthreads();
#pragma unroll
        for (int k = 0; k < BK; ++k) {
            float a[8], b[8];
            *reinterpret_cast<float4*>(&a[0]) = *reinterpret_cast<const float4*>(&As[k][ty * 8]);
            *reinterpret_cast<float4*>(&a[4]) = *reinterpret_cast<const float4*>(&As[k][ty * 8 + 4]);
            *reinterpret_cast<float4*>(&b[0]) = *reinterpret_cast<const float4*>(&Bs[k][tx * 8]);
            *reinterpret_cast<float4*>(&b[4]) = *reinterpret_cast<const float4*>(&Bs[k][tx * 8 + 4]);
#pragma unroll
            for (int i = 0; i < 8; ++i)
#pragma unroll
                for (int j = 0; j < 8; ++j)
                    acc[i][j] = fmaf(a[i], b[j], acc[i][j]);
        }
        __syncthreads();
    }

    float bv[8];
    *reinterpret_cast<float4*>(&bv[0]) = *reinterpret_cast<const float4*>(&bias[n0 + tx * 8]);
    *reinterpret_cast<float4*>(&bv[4]) = *reinterpret_cast<const float4*>(&bias[n0 + tx * 8 + 4]);
#pragma unroll
    for (int i = 0; i < 8; ++i) {
        us8 o;
#pragma unroll
        for (int j = 0; j < 8; ++j) o[j] = f2bf((acc[i][j] + bv[j]) * alpha);
        *reinterpret_cast<us8*>(&C[(size_t)(m0 + ty * 8 + i) * N + n0 + tx * 8]) = o;
    }
}

// ---------------- MFMA bf16 flash attention ----------------
// One block = 4 waves, 128 q rows of one (b,h) head. KV tile = 64 rows.
// Swapped QK^T: S^T = mfma(A=K, B=Q) so each lane holds P for q = lane&15.
// LDS holds K and V tiles in MFMA-fragment order: [blk16][m][slot=lane][h0|h1] 16B/slot.
__global__ __launch_bounds__(256, 2)
void attn_mfma(const unsigned short* __restrict__ Q, const unsigned short* __restrict__ K,
               const unsigned short* __restrict__ V, float* __restrict__ O)
{
    __shared__ __align__(16) unsigned short Kf[4 * 2 * 64 * 8];  // 8 KB
    __shared__ __align__(16) unsigned short Vf[4 * 2 * 64 * 8];  // 8 KB

    const int tid  = threadIdx.x;
    const int w    = tid >> 6;
    const int lane = tid & 63;
    const int l15  = lane & 15;
    const int g    = lane >> 4;

    const int qb = blockIdx.x;       // 0..15
    const int bh = blockIdx.y;       // 0..31
    const int b  = bh >> 4;
    const int hh = bh & 15;
    const size_t hoff = (size_t)b * S_ * E_ + (size_t)hh * S_ * D_;
    const unsigned short* Qh = Q + hoff;
    const unsigned short* Kh = K + hoff;
    const unsigned short* Vh = V + hoff;

    const int qw = qb * 128 + w * 32;

    // ---- Q fragments (persistent): qf[qg][m], elems 0-3 = h0, 4-7 = h1 ----
    short8 qf[2][2];
#pragma unroll
    for (int qg = 0; qg < 2; ++qg)
#pragma unroll
        for (int m = 0; m < 2; ++m) {
            const unsigned short* src = &Qh[(size_t)(qw + 16 * qg + l15) * D_ + 32 * m + 4 * g];
            us4 lo = *reinterpret_cast<const us4*>(src);
            us4 hi = *reinterpret_cast<const us4*>(src + 16);
            union { us4 h[2]; short8 s; } u;
            u.h[0] = lo; u.h[1] = hi;
            qf[qg][m] = u.s;
        }

    // staging assignments
    const int kr  = tid >> 2;          // K: row 0..63
    const int kc0 = tid & 3;           // K: 16B-chunk base
    const int kkc = tid >> 4;          // V: kk-chunk 0..15
    const int vdc = tid & 15;          // V: d-chunk 0..15
    const int vmc = kkc >> 3;
    const int vh  = (kkc >> 2) & 1;
    const int vg  = kkc & 3;
    const int vn  = vdc >> 2;

    f32x4 o[2][4];
#pragma unroll
    for (int qg = 0; qg < 2; ++qg)
#pragma unroll
        for (int n = 0; n < 4; ++n)
#pragma unroll
            for (int r = 0; r < 4; ++r) o[qg][n][r] = 0.f;

    float mrun[2] = {-1e30f, -1e30f};
    float lrun[2] = {0.f, 0.f};

    for (int kt = 0; kt < S_ / 64; ++kt) {
        // ---- global loads into regs (before barrier: overlaps prior compute) ----
        us8 kreg[2];
#pragma unroll
        for (int u = 0; u < 2; ++u) {
            const int c8 = kc0 + 4 * u;
            kreg[u] = *reinterpret_cast<const us8*>(&Kh[(size_t)(kt * 64 + kr) * D_ + 8 * c8]);
        }
        us4 vreg[4];
#pragma unroll
        for (int i = 0; i < 4; ++i)
            vreg[i] = *reinterpret_cast<const us4*>(&Vh[(size_t)(kt * 64 + 4 * kkc + i) * D_ + 4 * vdc]);

        __syncthreads();   // all waves done reading previous tile

        // ---- K writes: frag order [kkb][m][slot][h*4+i] ----
#pragma unroll
        for (int u = 0; u < 2; ++u) {
            const int c8 = kc0 + 4 * u;
            const int m = c8 >> 2;
            const int h = (c8 >> 1) & 1;
#pragma unroll
            for (int jh = 0; jh < 2; ++jh) {
                const int gk = (2 * c8 + jh) & 3;
                const int slot = gk * 16 + (kr & 15);
                us4 val;
#pragma unroll
                for (int i = 0; i < 4; ++i) val[i] = (unsigned short)kreg[u][4 * jh + i];
                *reinterpret_cast<us4*>(&Kf[((((kr >> 4) * 2 + m) * 64 + slot) * 8) + h * 4]) = val;
            }
        }
        // ---- V writes: transpose 4x4, frag order [n][m][slot][h*4+i] ----
#pragma unroll
        for (int jj = 0; jj < 4; ++jj) {
            us4 val;
#pragma unroll
            for (int i = 0; i < 4; ++i) val[i] = vreg[i][jj];
            const int slot = vg * 16 + 4 * (vdc & 3) + jj;
            *reinterpret_cast<us4*>(&Vf[(((vn * 2 + vmc) * 64 + slot) * 8) + vh * 4]) = val;
        }
        __syncthreads();

        // ---- K frags + QK^T (swapped: D[kk][q]) ----
        short8 kf[4][2];
#pragma unroll
        for (int kkb = 0; kkb < 4; ++kkb)
#pragma unroll
            for (int m = 0; m < 2; ++m)
                kf[kkb][m] = *reinterpret_cast<const short8*>(&Kf[((kkb * 2 + m) * 64 + lane) * 8]);

        f32x4 s[2][4];
#pragma unroll
        for (int qg = 0; qg < 2; ++qg)
#pragma unroll
            for (int kkb = 0; kkb < 4; ++kkb) {
                f32x4 z; z[0] = 0.f; z[1] = 0.f; z[2] = 0.f; z[3] = 0.f;
                z = __builtin_amdgcn_mfma_f32_16x16x32_bf16(kf[kkb][0], qf[qg][0], z, 0, 0, 0);
                s[qg][kkb] = __builtin_amdgcn_mfma_f32_16x16x32_bf16(kf[kkb][1], qf[qg][1], z, 0, 0, 0);
            }

        // ---- V frags ----
        short8 vf[4][2];
#pragma unroll
        for (int n = 0; n < 4; ++n)
#pragma unroll
            for (int m = 0; m < 2; ++m)
                vf[n][m] = *reinterpret_cast<const short8*>(&Vf[((n * 2 + m) * 64 + lane) * 8]);

        // ---- online softmax + PV per q-group ----
#pragma unroll
        for (int qg = 0; qg < 2; ++qg) {
            float t = s[qg][0][0];
#pragma unroll
            for (int kkb = 0; kkb < 4; ++kkb)
#pragma unroll
                for (int r = 0; r < 4; ++r) t = fmaxf(t, s[qg][kkb][r]);
            t = fmaxf(t, __shfl_xor(t, 16));
            t = fmaxf(t, __shfl_xor(t, 32));
            const float mnew = fmaxf(mrun[qg], t);
            const float corr = __builtin_amdgcn_exp2f(mrun[qg] - mnew);

            float rs = 0.f;
#pragma unroll
            for (int kkb = 0; kkb < 4; ++kkb)
#pragma unroll
                for (int r = 0; r < 4; ++r) {
                    const float p = __builtin_amdgcn_exp2f(s[qg][kkb][r] - mnew);
                    s[qg][kkb][r] = p;
                    rs += p;
                }
            rs += __shfl_xor(rs, 16);
            rs += __shfl_xor(rs, 32);
            lrun[qg] = lrun[qg] * corr + rs;
            mrun[qg] = mnew;

            // rescale O rows (row q' = 4g + r needs corr from lane 4g+r)
#pragma unroll
            for (int r = 0; r < 4; ++r) {
                const float c4 = __shfl(corr, 4 * g + r);
#pragma unroll
                for (int n = 0; n < 4; ++n) o[qg][n][r] *= c4;
            }

            // P -> bf16 A-fragments: pa[m] elems 0-3 = blk 2m, 4-7 = blk 2m+1
            short8 pa[2];
#pragma unroll
            for (int m = 0; m < 2; ++m) {
                us8 tmp;
#pragma unroll
                for (int r = 0; r < 4; ++r) {
                    tmp[r]     = f2bf(s[qg][2 * m][r]);
                    tmp[r + 4] = f2bf(s[qg][2 * m + 1][r]);
                }
                union { us8 u8; short8 s8; } cvt; cvt.u8 = tmp;
                pa[m] = cvt.s8;
            }
#pragma unroll
            for (int n = 0; n < 4; ++n) {
                o[qg][n] = __builtin_amdgcn_mfma_f32_16x16x32_bf16(pa[0], vf[n][0], o[qg][n], 0, 0, 0);
                o[qg][n] = __builtin_amdgcn_mfma_f32_16x16x32_bf16(pa[1], vf[n][1], o[qg][n], 0, 0, 0);
            }
        }
    }

    // ---- epilogue: divide by l, write XH[b][s][hh*64+d] ----
#pragma unroll
    for (int qg = 0; qg < 2; ++qg) {
        const float invl = 1.f / lrun[qg];
#pragma unroll
        for (int r = 0; r < 4; ++r) {
            const float iv = __shfl(invl, 4 * g + r);
            const int row = qw + 16 * qg + 4 * g + r;
            float* dst = &O[((size_t)b * S_ + row) * E_ + hh * D_ + l15];
            dst[0]  = o[qg][0][r] * iv;
            dst[16] = o[qg][1][r] * iv;
            dst[32] = o[qg][2][r] * iv;
            dst[48] = o[qg][3][r] * iv;
        }
    }
}

extern "C" void kernel_launch(void* const* d_in, const int* in_sizes, int n_in,
                              void* d_out, int out_size, void* d_ws, size_t ws_size,
                              hipStream_t stream) {
    (void)in_sizes; (void)n_in; (void)out_size; (void)ws_size;
    const float* x  = (const float*)d_in[0];
    const float* Wq = (const float*)d_in[1];
    const float* bq = (const float*)d_in[2];
    const float* Wk = (const float*)d_in[3];
    const float* bk = (const float*)d_in[4];
    const float* Wv = (const float*)d_in[5];
    const float* bv = (const float*)d_in[6];
    const float* Wo = (const float*)d_in[7];
    const float* bo = (const float*)d_in[8];
    float* out = (float*)d_out;

    const size_t NE = (size_t)B_ * S_ * E_;          // 4,194,304
    unsigned short* Qb = (unsigned short*)d_ws;
    unsigned short* Kb = Qb + NE;
    unsigned short* Vb = Kb + NE;
    float* XH = (float*)(Vb + NE);                   // 25.2MB offset, 16B aligned

    const float qalpha = 0.125f * 1.4426950408889634f;  // 1/sqrt(D) * log2(e)

    dim3 blk(256);
    dim3 ggrid(E_ / 128, (B_ * S_) / 128);           // (8, 32)
    gemm_bias_bf16out<<<ggrid, blk, 0, stream>>>(x, Wq, bq, Qb, B_ * S_, E_, E_, qalpha);
    gemm_bias_bf16out<<<ggrid, blk, 0, stream>>>(x, Wk, bk, Kb, B_ * S_, E_, E_, 1.0f);
    gemm_bias_bf16out<<<ggrid, blk, 0, stream>>>(x, Wv, bv, Vb, B_ * S_, E_, E_, 1.0f);

    dim3 agrid(S_ / 128, B_ * H_);                   // (16, 32)
    attn_mfma<<<agrid, blk, 0, stream>>>(Qb, Kb, Vb, XH);

    gemm_bias_f32<<<ggrid, blk, 0, stream>>>(XH, Wo, bo, out, B_ * S_, E_, E_);
}

// Round 3
// 359.362 us; speedup vs baseline: 5.2748x; 1.8364x over previous
//
#include <hip/hip_runtime.h>
#include <math.h>

#define B_ 2
#define S_ 2048
#define E_ 1024
#define H_ 16
#define D_ 64

typedef __attribute__((ext_vector_type(8))) short short8;
typedef __attribute__((ext_vector_type(4))) float f32x4;
typedef __attribute__((ext_vector_type(4))) unsigned short us4;
typedef __attribute__((ext_vector_type(8))) unsigned short us8;
typedef unsigned short ushort_t;

__device__ __forceinline__ ushort_t f2bf(float f) {
    unsigned int u = __float_as_uint(f);
    u += 0x7FFFu + ((u >> 16) & 1u);
    return (ushort_t)(u >> 16);
}
__device__ __forceinline__ float bf2f(ushort_t h) {
    return __uint_as_float((unsigned int)h << 16);
}

// async global->LDS, 16B per lane; LDS dest = wave-uniform base + lane*16
__device__ __forceinline__ void gload16(const void* g, void* l) {
    __builtin_amdgcn_global_load_lds(
        (__attribute__((address_space(1))) void*)(unsigned long long)g,
        (__attribute__((address_space(3))) void*)(unsigned int)(unsigned long long)l,
        16, 0, 0);
}

// ---------------- x -> (hi, lo) bf16 split ----------------
__global__ __launch_bounds__(256)
void split_x(const float* __restrict__ in, ushort_t* __restrict__ hi,
             ushort_t* __restrict__ lo)
{
    const size_t base = ((size_t)blockIdx.x * 256 + threadIdx.x) * 8;
    float v[8];
    *reinterpret_cast<float4*>(&v[0]) = *reinterpret_cast<const float4*>(&in[base]);
    *reinterpret_cast<float4*>(&v[4]) = *reinterpret_cast<const float4*>(&in[base + 4]);
    us8 h, l;
#pragma unroll
    for (int j = 0; j < 8; ++j) {
        ushort_t hh = f2bf(v[j]);
        h[j] = hh;
        l[j] = f2bf(v[j] - bf2f(hh));
    }
    *reinterpret_cast<us8*>(&hi[base]) = h;
    *reinterpret_cast<us8*>(&lo[base]) = l;
}

// ---------------- W[k][n] -> Wt[z][n][k] hi/lo bf16 (transpose + split) ----------------
__global__ __launch_bounds__(256)
void wsplit_t(const float* __restrict__ Wq, const float* __restrict__ Wk,
              const float* __restrict__ Wv, const float* __restrict__ Wo,
              ushort_t* __restrict__ Wth, ushort_t* __restrict__ Wtl)
{
    __shared__ float T[64][65];
    const int tid = threadIdx.x;
    const int z = blockIdx.z;
    const float* W = (z == 0) ? Wq : (z == 1) ? Wk : (z == 2) ? Wv : Wo;
    const int kt = blockIdx.y * 64;
    const int nt = blockIdx.x * 64;

    const int lr = (tid >> 4) * 4;
    const int lc = (tid & 15) * 4;
#pragma unroll
    for (int i = 0; i < 4; ++i) {
        float4 v = *reinterpret_cast<const float4*>(&W[(size_t)(kt + lr + i) * 1024 + nt + lc]);
        T[lr + i][lc + 0] = v.x; T[lr + i][lc + 1] = v.y;
        T[lr + i][lc + 2] = v.z; T[lr + i][lc + 3] = v.w;
    }
    __syncthreads();

    const int n = tid >> 2;            // 0..63
    const int kc = (tid & 3) * 16;     // 0,16,32,48
    us8 h[2], l[2];
#pragma unroll
    for (int u = 0; u < 2; ++u)
#pragma unroll
        for (int j = 0; j < 8; ++j) {
            float v = T[kc + u * 8 + j][n];
            ushort_t hh = f2bf(v);
            h[u][j] = hh;
            l[u][j] = f2bf(v - bf2f(hh));
        }
    ushort_t* dh = Wth + ((size_t)z * 1024 + nt + n) * 1024 + kt + kc;
    ushort_t* dl = Wtl + ((size_t)z * 1024 + nt + n) * 1024 + kt + kc;
    *reinterpret_cast<us8*>(dh)     = h[0];
    *reinterpret_cast<us8*>(dh + 8) = h[1];
    *reinterpret_cast<us8*>(dl)     = l[0];
    *reinterpret_cast<us8*>(dl + 8) = l[1];
}

// ---------------- bf16x3 MFMA GEMM core: 128x128 tile, BK=32, K=1024 ----------------
// A (hi/lo): row-major [M][1024] bf16.  B (hi/lo): row-major [N=.. ][1024] (transposed W).
// acc[mb][nb]: wave (wr,wc) covers 64x64; frag row/col = base + mb/nb*16 + l15.
__device__ __forceinline__ void gemm128_core(
    const ushort_t* __restrict__ Ah, const ushort_t* __restrict__ Al,
    const ushort_t* __restrict__ Bh, const ushort_t* __restrict__ Bl,
    int m0, int n0,
    ushort_t* AsH, ushort_t* AsL, ushort_t* BsH, ushort_t* BsL,
    f32x4 acc[4][4])
{
    const int tid  = threadIdx.x;
    const int lane = tid & 63;
    const int w    = tid >> 6;
    const int l15  = lane & 15;
    const int g    = lane >> 4;
    const int wr   = w >> 1;
    const int wc   = w & 1;

    const int sr = lane >> 2;
    const int sc = (lane & 3) * 8;
    const int j0 = w * 2, j1 = j0 + 1;

    const ushort_t* gAh0 = Ah + (size_t)(m0 + j0 * 16 + sr) * 1024 + sc;
    const ushort_t* gAh1 = Ah + (size_t)(m0 + j1 * 16 + sr) * 1024 + sc;
    const ushort_t* gAl0 = Al + (size_t)(m0 + j0 * 16 + sr) * 1024 + sc;
    const ushort_t* gAl1 = Al + (size_t)(m0 + j1 * 16 + sr) * 1024 + sc;
    const ushort_t* gBh0 = Bh + (size_t)(n0 + j0 * 16 + sr) * 1024 + sc;
    const ushort_t* gBh1 = Bh + (size_t)(n0 + j1 * 16 + sr) * 1024 + sc;
    const ushort_t* gBl0 = Bl + (size_t)(n0 + j0 * 16 + sr) * 1024 + sc;
    const ushort_t* gBl1 = Bl + (size_t)(n0 + j1 * 16 + sr) * 1024 + sc;

    for (int kt = 0; kt < 32; ++kt) {
        const int k0 = kt * 32;
        if (kt) __syncthreads();
        gload16(gAh0 + k0, AsH + j0 * 512);
        gload16(gAh1 + k0, AsH + j1 * 512);
        gload16(gAl0 + k0, AsL + j0 * 512);
        gload16(gAl1 + k0, AsL + j1 * 512);
        gload16(gBh0 + k0, BsH + j0 * 512);
        gload16(gBh1 + k0, BsH + j1 * 512);
        gload16(gBl0 + k0, BsL + j0 * 512);
        gload16(gBl1 + k0, BsL + j1 * 512);
        asm volatile("s_waitcnt vmcnt(0)" ::: "memory");
        __syncthreads();

        short8 bh[4], bl[4];
#pragma unroll
        for (int nb = 0; nb < 4; ++nb) {
            const ushort_t* p = BsH + (wc * 64 + nb * 16 + l15) * 32 + 4 * g;
            union { us4 h[2]; short8 s; } u;
            u.h[0] = *reinterpret_cast<const us4*>(p);
            u.h[1] = *reinterpret_cast<const us4*>(p + 16);
            bh[nb] = u.s;
            const ushort_t* q = BsL + (wc * 64 + nb * 16 + l15) * 32 + 4 * g;
            union { us4 h[2]; short8 s; } v;
            v.h[0] = *reinterpret_cast<const us4*>(q);
            v.h[1] = *reinterpret_cast<const us4*>(q + 16);
            bl[nb] = v.s;
        }
#pragma unroll
        for (int mb = 0; mb < 4; ++mb) {
            const ushort_t* pa = AsH + (wr * 64 + mb * 16 + l15) * 32 + 4 * g;
            union { us4 h[2]; short8 s; } ua;
            ua.h[0] = *reinterpret_cast<const us4*>(pa);
            ua.h[1] = *reinterpret_cast<const us4*>(pa + 16);
            const ushort_t* pl = AsL + (wr * 64 + mb * 16 + l15) * 32 + 4 * g;
            union { us4 h[2]; short8 s; } ul;
            ul.h[0] = *reinterpret_cast<const us4*>(pl);
            ul.h[1] = *reinterpret_cast<const us4*>(pl + 16);
            const short8 ah = ua.s, al = ul.s;
#pragma unroll
            for (int nb = 0; nb < 4; ++nb) {
                acc[mb][nb] = __builtin_amdgcn_mfma_f32_16x16x32_bf16(ah, bh[nb], acc[mb][nb], 0, 0, 0);
                acc[mb][nb] = __builtin_amdgcn_mfma_f32_16x16x32_bf16(al, bh[nb], acc[mb][nb], 0, 0, 0);
                acc[mb][nb] = __builtin_amdgcn_mfma_f32_16x16x32_bf16(ah, bl[nb], acc[mb][nb], 0, 0, 0);
            }
        }
    }
}

// ---------------- fused QKV GEMM (bf16 out, alpha fold) ----------------
__global__ __launch_bounds__(256, 3)
void gemm_qkv(const ushort_t* __restrict__ xh, const ushort_t* __restrict__ xl,
              const ushort_t* __restrict__ Wth, const ushort_t* __restrict__ Wtl,
              const float* __restrict__ bq, const float* __restrict__ bk,
              const float* __restrict__ bv,
              ushort_t* __restrict__ Qb, ushort_t* __restrict__ Kb,
              ushort_t* __restrict__ Vb, float qalpha)
{
    __shared__ ushort_t AsH[128 * 32], AsL[128 * 32], BsH[128 * 32], BsL[128 * 32];
    const int which = blockIdx.x >> 3;
    const int n0 = (blockIdx.x & 7) * 128;
    const int m0 = blockIdx.y * 128;
    const ushort_t* Bh = Wth + (size_t)which * 1024 * 1024;
    const ushort_t* Bl = Wtl + (size_t)which * 1024 * 1024;
    const float* bias = (which == 0) ? bq : (which == 1) ? bk : bv;
    ushort_t* out = (which == 0) ? Qb : (which == 1) ? Kb : Vb;
    const float alpha = (which == 0) ? qalpha : 1.0f;

    f32x4 acc[4][4];
#pragma unroll
    for (int i = 0; i < 4; ++i)
#pragma unroll
        for (int j = 0; j < 4; ++j) { acc[i][j][0] = 0.f; acc[i][j][1] = 0.f; acc[i][j][2] = 0.f; acc[i][j][3] = 0.f; }

    gemm128_core(xh, xl, Bh, Bl, m0, n0, AsH, AsL, BsH, BsL, acc);

    const int tid = threadIdx.x;
    const int lane = tid & 63, l15 = lane & 15, g = lane >> 4;
    const int w = tid >> 6, wr = w >> 1, wc = w & 1;
    float bvv[4];
#pragma unroll
    for (int nb = 0; nb < 4; ++nb) bvv[nb] = bias[n0 + wc * 64 + nb * 16 + l15];
#pragma unroll
    for (int mb = 0; mb < 4; ++mb)
#pragma unroll
        for (int r = 0; r < 4; ++r) {
            const size_t row = m0 + wr * 64 + mb * 16 + 4 * g + r;
#pragma unroll
            for (int nb = 0; nb < 4; ++nb) {
                const float vv = (acc[mb][nb][r] + bvv[nb]) * alpha;
                out[row * 1024 + n0 + wc * 64 + nb * 16 + l15] = f2bf(vv);
            }
        }
}

// ---------------- output GEMM (fp32 out) ----------------
__global__ __launch_bounds__(256, 3)
void gemm_o(const ushort_t* __restrict__ Ah, const ushort_t* __restrict__ Al,
            const ushort_t* __restrict__ Bh, const ushort_t* __restrict__ Bl,
            const float* __restrict__ bias, float* __restrict__ out)
{
    __shared__ ushort_t AsH[128 * 32], AsL[128 * 32], BsH[128 * 32], BsL[128 * 32];
    const int n0 = blockIdx.x * 128;
    const int m0 = blockIdx.y * 128;

    f32x4 acc[4][4];
#pragma unroll
    for (int i = 0; i < 4; ++i)
#pragma unroll
        for (int j = 0; j < 4; ++j) { acc[i][j][0] = 0.f; acc[i][j][1] = 0.f; acc[i][j][2] = 0.f; acc[i][j][3] = 0.f; }

    gemm128_core(Ah, Al, Bh, Bl, m0, n0, AsH, AsL, BsH, BsL, acc);

    const int tid = threadIdx.x;
    const int lane = tid & 63, l15 = lane & 15, g = lane >> 4;
    const int w = tid >> 6, wr = w >> 1, wc = w & 1;
    float bvv[4];
#pragma unroll
    for (int nb = 0; nb < 4; ++nb) bvv[nb] = bias[n0 + wc * 64 + nb * 16 + l15];
#pragma unroll
    for (int mb = 0; mb < 4; ++mb)
#pragma unroll
        for (int r = 0; r < 4; ++r) {
            const size_t row = m0 + wr * 64 + mb * 16 + 4 * g + r;
#pragma unroll
            for (int nb = 0; nb < 4; ++nb)
                out[row * 1024 + n0 + wc * 64 + nb * 16 + l15] = acc[mb][nb][r] + bvv[nb];
        }
}

// ---------------- MFMA bf16 flash attention (round-2 verified core) ----------------
__global__ __launch_bounds__(256, 2)
void attn_mfma(const ushort_t* __restrict__ Q, const ushort_t* __restrict__ K,
               const ushort_t* __restrict__ V, ushort_t* __restrict__ XHh,
               ushort_t* __restrict__ XHl)
{
    __shared__ __align__(16) ushort_t Kf[4 * 2 * 64 * 8];
    __shared__ __align__(16) ushort_t Vf[4 * 2 * 64 * 8];

    const int tid  = threadIdx.x;
    const int w    = tid >> 6;
    const int lane = tid & 63;
    const int l15  = lane & 15;
    const int g    = lane >> 4;

    const int qb = blockIdx.x;
    const int bh = blockIdx.y;
    const int b  = bh >> 4;
    const int hh = bh & 15;
    const size_t hoff = (size_t)b * S_ * E_ + (size_t)hh * S_ * D_;
    const ushort_t* Qh = Q + hoff;
    const ushort_t* Kh = K + hoff;
    const ushort_t* Vh = V + hoff;

    const int qw = qb * 128 + w * 32;

    short8 qf[2][2];
#pragma unroll
    for (int qg = 0; qg < 2; ++qg)
#pragma unroll
        for (int m = 0; m < 2; ++m) {
            const ushort_t* src = &Qh[(size_t)(qw + 16 * qg + l15) * D_ + 32 * m + 4 * g];
            us4 lo = *reinterpret_cast<const us4*>(src);
            us4 hi = *reinterpret_cast<const us4*>(src + 16);
            union { us4 h[2]; short8 s; } u;
            u.h[0] = lo; u.h[1] = hi;
            qf[qg][m] = u.s;
        }

    const int kr  = tid >> 2;
    const int kc0 = tid & 3;
    const int kkc = tid >> 4;
    const int vdc = tid & 15;
    const int vmc = kkc >> 3;
    const int vh  = (kkc >> 2) & 1;
    const int vg  = kkc & 3;
    const int vn  = vdc >> 2;

    f32x4 o[2][4];
#pragma unroll
    for (int qg = 0; qg < 2; ++qg)
#pragma unroll
        for (int n = 0; n < 4; ++n)
#pragma unroll
            for (int r = 0; r < 4; ++r) o[qg][n][r] = 0.f;

    float mrun[2] = {-1e30f, -1e30f};
    float lrun[2] = {0.f, 0.f};

    for (int kt = 0; kt < S_ / 64; ++kt) {
        us8 kreg[2];
#pragma unroll
        for (int u = 0; u < 2; ++u) {
            const int c8 = kc0 + 4 * u;
            kreg[u] = *reinterpret_cast<const us8*>(&Kh[(size_t)(kt * 64 + kr) * D_ + 8 * c8]);
        }
        us4 vreg[4];
#pragma unroll
        for (int i = 0; i < 4; ++i)
            vreg[i] = *reinterpret_cast<const us4*>(&Vh[(size_t)(kt * 64 + 4 * kkc + i) * D_ + 4 * vdc]);

        __syncthreads();

#pragma unroll
        for (int u = 0; u < 2; ++u) {
            const int c8 = kc0 + 4 * u;
            const int m = c8 >> 2;
            const int h = (c8 >> 1) & 1;
#pragma unroll
            for (int jh = 0; jh < 2; ++jh) {
                const int gk = (2 * c8 + jh) & 3;
                const int slot = gk * 16 + (kr & 15);
                us4 val;
#pragma unroll
                for (int i = 0; i < 4; ++i) val[i] = (ushort_t)kreg[u][4 * jh + i];
                *reinterpret_cast<us4*>(&Kf[((((kr >> 4) * 2 + m) * 64 + slot) * 8) + h * 4]) = val;
            }
        }
#pragma unroll
        for (int jj = 0; jj < 4; ++jj) {
            us4 val;
#pragma unroll
            for (int i = 0; i < 4; ++i) val[i] = vreg[i][jj];
            const int slot = vg * 16 + 4 * (vdc & 3) + jj;
            *reinterpret_cast<us4*>(&Vf[(((vn * 2 + vmc) * 64 + slot) * 8) + vh * 4]) = val;
        }
        __syncthreads();

        short8 kf[4][2];
#pragma unroll
        for (int kkb = 0; kkb < 4; ++kkb)
#pragma unroll
            for (int m = 0; m < 2; ++m)
                kf[kkb][m] = *reinterpret_cast<const short8*>(&Kf[((kkb * 2 + m) * 64 + lane) * 8]);

        f32x4 s[2][4];
#pragma unroll
        for (int qg = 0; qg < 2; ++qg)
#pragma unroll
            for (int kkb = 0; kkb < 4; ++kkb) {
                f32x4 z; z[0] = 0.f; z[1] = 0.f; z[2] = 0.f; z[3] = 0.f;
                z = __builtin_amdgcn_mfma_f32_16x16x32_bf16(kf[kkb][0], qf[qg][0], z, 0, 0, 0);
                s[qg][kkb] = __builtin_amdgcn_mfma_f32_16x16x32_bf16(kf[kkb][1], qf[qg][1], z, 0, 0, 0);
            }

        short8 vf[4][2];
#pragma unroll
        for (int n = 0; n < 4; ++n)
#pragma unroll
            for (int m = 0; m < 2; ++m)
                vf[n][m] = *reinterpret_cast<const short8*>(&Vf[((n * 2 + m) * 64 + lane) * 8]);

#pragma unroll
        for (int qg = 0; qg < 2; ++qg) {
            float t = s[qg][0][0];
#pragma unroll
            for (int kkb = 0; kkb < 4; ++kkb)
#pragma unroll
                for (int r = 0; r < 4; ++r) t = fmaxf(t, s[qg][kkb][r]);
            t = fmaxf(t, __shfl_xor(t, 16));
            t = fmaxf(t, __shfl_xor(t, 32));
            const float mnew = fmaxf(mrun[qg], t);
            const float corr = __builtin_amdgcn_exp2f(mrun[qg] - mnew);

            float rs = 0.f;
#pragma unroll
            for (int kkb = 0; kkb < 4; ++kkb)
#pragma unroll
                for (int r = 0; r < 4; ++r) {
                    const float p = __builtin_amdgcn_exp2f(s[qg][kkb][r] - mnew);
                    s[qg][kkb][r] = p;
                    rs += p;
                }
            rs += __shfl_xor(rs, 16);
            rs += __shfl_xor(rs, 32);
            lrun[qg] = lrun[qg] * corr + rs;
            mrun[qg] = mnew;

#pragma unroll
            for (int r = 0; r < 4; ++r) {
                const float c4 = __shfl(corr, 4 * g + r);
#pragma unroll
                for (int n = 0; n < 4; ++n) o[qg][n][r] *= c4;
            }

            short8 pa[2];
#pragma unroll
            for (int m = 0; m < 2; ++m) {
                us8 tmp;
#pragma unroll
                for (int r = 0; r < 4; ++r) {
                    tmp[r]     = f2bf(s[qg][2 * m][r]);
                    tmp[r + 4] = f2bf(s[qg][2 * m + 1][r]);
                }
                union { us8 u8; short8 s8; } cvt; cvt.u8 = tmp;
                pa[m] = cvt.s8;
            }
#pragma unroll
            for (int n = 0; n < 4; ++n) {
                o[qg][n] = __builtin_amdgcn_mfma_f32_16x16x32_bf16(pa[0], vf[n][0], o[qg][n], 0, 0, 0);
                o[qg][n] = __builtin_amdgcn_mfma_f32_16x16x32_bf16(pa[1], vf[n][1], o[qg][n], 0, 0, 0);
            }
        }
    }

    // epilogue: divide by l, write hi/lo bf16 XH[b][s][hh*64+d]
#pragma unroll
    for (int qg = 0; qg < 2; ++qg) {
        const float invl = 1.f / lrun[qg];
#pragma unroll
        for (int r = 0; r < 4; ++r) {
            const float iv = __shfl(invl, 4 * g + r);
            const int row = qw + 16 * qg + 4 * g + r;
            const size_t base = ((size_t)b * S_ + row) * E_ + hh * D_ + l15;
#pragma unroll
            for (int n = 0; n < 4; ++n) {
                const float vv = o[qg][n][r] * iv;
                const ushort_t hi = f2bf(vv);
                XHh[base + 16 * n] = hi;
                XHl[base + 16 * n] = f2bf(vv - bf2f(hi));
            }
        }
    }
}

extern "C" void kernel_launch(void* const* d_in, const int* in_sizes, int n_in,
                              void* d_out, int out_size, void* d_ws, size_t ws_size,
                              hipStream_t stream) {
    (void)in_sizes; (void)n_in; (void)out_size; (void)ws_size;
    const float* x  = (const float*)d_in[0];
    const float* Wq = (const float*)d_in[1];
    const float* bq = (const float*)d_in[2];
    const float* Wk = (const float*)d_in[3];
    const float* bk = (const float*)d_in[4];
    const float* Wv = (const float*)d_in[5];
    const float* bv = (const float*)d_in[6];
    const float* Wo = (const float*)d_in[7];
    const float* bo = (const float*)d_in[8];
    float* out = (float*)d_out;

    char* ws = (char*)d_ws;
    const size_t MB8 = 8ull * 1024 * 1024;
    ushort_t* xhi = (ushort_t*)(ws);             // 8 MB, reused as XHh after QKV
    ushort_t* xlo = (ushort_t*)(ws + MB8);       // 8 MB, reused as XHl
    ushort_t* Wth = (ushort_t*)(ws + 2 * MB8);   // 8 MB  [4][1024][1024]
    ushort_t* Wtl = (ushort_t*)(ws + 3 * MB8);   // 8 MB
    ushort_t* Qb  = (ushort_t*)(ws + 4 * MB8);   // 8 MB
    ushort_t* Kb  = (ushort_t*)(ws + 5 * MB8);   // 8 MB
    ushort_t* Vb  = (ushort_t*)(ws + 6 * MB8);   // 8 MB  (total 56 MB)
    ushort_t* XHh = xhi;
    ushort_t* XHl = xlo;

    const float qalpha = 0.125f * 1.4426950408889634f;  // 1/sqrt(D) * log2(e)

    split_x<<<dim3(2048), dim3(256), 0, stream>>>(x, xhi, xlo);
    wsplit_t<<<dim3(16, 16, 4), dim3(256), 0, stream>>>(Wq, Wk, Wv, Wo, Wth, Wtl);

    gemm_qkv<<<dim3(24, 32), dim3(256), 0, stream>>>(xhi, xlo, Wth, Wtl,
                                                     bq, bk, bv, Qb, Kb, Vb, qalpha);

    attn_mfma<<<dim3(16, 32), dim3(256), 0, stream>>>(Qb, Kb, Vb, XHh, XHl);

    gemm_o<<<dim3(8, 32), dim3(256), 0, stream>>>(XHh, XHl,
                                                  Wth + 3ull * 1024 * 1024,
                                                  Wtl + 3ull * 1024 * 1024,
                                                  bo, out);
}

// Round 4
// 224.756 us; speedup vs baseline: 8.4338x; 1.5989x over previous
//
#include <hip/hip_runtime.h>
#include <math.h>

#define B_ 2
#define S_ 2048
#define E_ 1024
#define H_ 16
#define D_ 64

typedef __attribute__((ext_vector_type(8))) short short8;
typedef __attribute__((ext_vector_type(4))) float f32x4;
typedef __attribute__((ext_vector_type(4))) unsigned short us4;
typedef __attribute__((ext_vector_type(8))) unsigned short us8;
typedef unsigned short ushort_t;

__device__ __forceinline__ ushort_t f2bf(float f) {
    unsigned int u = __float_as_uint(f);
    u += 0x7FFFu + ((u >> 16) & 1u);
    return (ushort_t)(u >> 16);
}
__device__ __forceinline__ float bf2f(ushort_t h) {
    return __uint_as_float((unsigned int)h << 16);
}

// async global->LDS, 16B per lane; LDS dest = wave-uniform base + lane*16
__device__ __forceinline__ void gload16(const void* g, void* l) {
    __builtin_amdgcn_global_load_lds(
        (__attribute__((address_space(1))) void*)(unsigned long long)g,
        (__attribute__((address_space(3))) void*)(unsigned int)(unsigned long long)l,
        16, 0, 0);
}

// ---------------- x -> (hi, lo) bf16 split ----------------
__global__ __launch_bounds__(256)
void split_x(const float* __restrict__ in, ushort_t* __restrict__ hi,
             ushort_t* __restrict__ lo)
{
    const size_t base = ((size_t)blockIdx.x * 256 + threadIdx.x) * 8;
    float v[8];
    *reinterpret_cast<float4*>(&v[0]) = *reinterpret_cast<const float4*>(&in[base]);
    *reinterpret_cast<float4*>(&v[4]) = *reinterpret_cast<const float4*>(&in[base + 4]);
    us8 h, l;
#pragma unroll
    for (int j = 0; j < 8; ++j) {
        ushort_t hh = f2bf(v[j]);
        h[j] = hh;
        l[j] = f2bf(v[j] - bf2f(hh));
    }
    *reinterpret_cast<us8*>(&hi[base]) = h;
    *reinterpret_cast<us8*>(&lo[base]) = l;
}

// ---------------- W[k][n] -> Wt[z][n][k] hi/lo bf16 (transpose + split) ----------------
__global__ __launch_bounds__(256)
void wsplit_t(const float* __restrict__ Wq, const float* __restrict__ Wk,
              const float* __restrict__ Wv, const float* __restrict__ Wo,
              ushort_t* __restrict__ Wth, ushort_t* __restrict__ Wtl)
{
    __shared__ float T[64][65];
    const int tid = threadIdx.x;
    const int z = blockIdx.z;
    const float* W = (z == 0) ? Wq : (z == 1) ? Wk : (z == 2) ? Wv : Wo;
    const int kt = blockIdx.y * 64;
    const int nt = blockIdx.x * 64;

    const int lr = (tid >> 4) * 4;
    const int lc = (tid & 15) * 4;
#pragma unroll
    for (int i = 0; i < 4; ++i) {
        float4 v = *reinterpret_cast<const float4*>(&W[(size_t)(kt + lr + i) * 1024 + nt + lc]);
        T[lr + i][lc + 0] = v.x; T[lr + i][lc + 1] = v.y;
        T[lr + i][lc + 2] = v.z; T[lr + i][lc + 3] = v.w;
    }
    __syncthreads();

    const int n = tid >> 2;            // 0..63
    const int kc = (tid & 3) * 16;     // 0,16,32,48
    us8 h[2], l[2];
#pragma unroll
    for (int u = 0; u < 2; ++u)
#pragma unroll
        for (int j = 0; j < 8; ++j) {
            float v = T[kc + u * 8 + j][n];
            ushort_t hh = f2bf(v);
            h[u][j] = hh;
            l[u][j] = f2bf(v - bf2f(hh));
        }
    ushort_t* dh = Wth + ((size_t)z * 1024 + nt + n) * 1024 + kt + kc;
    ushort_t* dl = Wtl + ((size_t)z * 1024 + nt + n) * 1024 + kt + kc;
    *reinterpret_cast<us8*>(dh)     = h[0];
    *reinterpret_cast<us8*>(dh + 8) = h[1];
    *reinterpret_cast<us8*>(dl)     = l[0];
    *reinterpret_cast<us8*>(dl + 8) = l[1];
}

// ---------------- bf16x3 MFMA GEMM core: 128x128 tile, BK=32, K=1024 ----------------
// LDS tile layout: [8 j-blocks][16 rows][4 chunks of 16B], with XOR swizzle:
// LDS chunk position cpos holds global k-chunk (cpos ^ ((row&15)>>1 & 3)).
// Source pre-swizzled (gload_lds writes linearly); reads apply the same XOR.
// => all fragment ds_reads are 2-way banked (free, m136).
__device__ __forceinline__ void gemm128_core(
    const ushort_t* __restrict__ Ah, const ushort_t* __restrict__ Al,
    const ushort_t* __restrict__ Bh, const ushort_t* __restrict__ Bl,
    int m0, int n0,
    ushort_t* AsH, ushort_t* AsL, ushort_t* BsH, ushort_t* BsL,
    f32x4 acc[4][4])
{
    const int tid  = threadIdx.x;
    const int lane = tid & 63;
    const int w    = tid >> 6;
    const int l15  = lane & 15;
    const int g    = lane >> 4;
    const int wr   = w >> 1;
    const int wc   = w & 1;

    // staging: lane's global source = row sr, k-chunk (lane&3)^((sr>>1)&3)
    const int sr  = lane >> 2;
    const int scz = (lane & 3) ^ ((sr >> 1) & 3);
    const int sc  = scz * 8;                       // shorts
    const int j0 = w * 2, j1 = j0 + 1;

    const ushort_t* gAh0 = Ah + (size_t)(m0 + j0 * 16 + sr) * 1024 + sc;
    const ushort_t* gAh1 = Ah + (size_t)(m0 + j1 * 16 + sr) * 1024 + sc;
    const ushort_t* gAl0 = Al + (size_t)(m0 + j0 * 16 + sr) * 1024 + sc;
    const ushort_t* gAl1 = Al + (size_t)(m0 + j1 * 16 + sr) * 1024 + sc;
    const ushort_t* gBh0 = Bh + (size_t)(n0 + j0 * 16 + sr) * 1024 + sc;
    const ushort_t* gBh1 = Bh + (size_t)(n0 + j1 * 16 + sr) * 1024 + sc;
    const ushort_t* gBl0 = Bl + (size_t)(n0 + j0 * 16 + sr) * 1024 + sc;
    const ushort_t* gBl1 = Bl + (size_t)(n0 + j1 * 16 + sr) * 1024 + sc;

    // read-side swizzle constants (per thread)
    const int sx  = (l15 >> 1) & 3;
    const int c1s = ((g >> 1) + 0) ^ sx;   // swizzled chunk holding k=4g..4g+3
    const int c2s = ((g >> 1) + 2) ^ sx;   // swizzled chunk holding k=4g+16..+19
    const int o1  = (g & 1) * 4;           // shorts within 16B chunk
    const int rd1 = c1s * 8 + o1;
    const int rd2 = c2s * 8 + o1;

    for (int kt = 0; kt < 32; ++kt) {
        const int k0 = kt * 32;
        if (kt) __syncthreads();
        gload16(gAh0 + k0, AsH + j0 * 512);
        gload16(gAh1 + k0, AsH + j1 * 512);
        gload16(gAl0 + k0, AsL + j0 * 512);
        gload16(gAl1 + k0, AsL + j1 * 512);
        gload16(gBh0 + k0, BsH + j0 * 512);
        gload16(gBh1 + k0, BsH + j1 * 512);
        gload16(gBl0 + k0, BsL + j0 * 512);
        gload16(gBl1 + k0, BsL + j1 * 512);
        asm volatile("s_waitcnt vmcnt(0)" ::: "memory");
        __syncthreads();

        short8 bh[4], bl[4];
#pragma unroll
        for (int nb = 0; nb < 4; ++nb) {
            const int rbase = (wc * 64 + nb * 16 + l15) * 32;
            union { us4 h[2]; short8 s; } u;
            u.h[0] = *reinterpret_cast<const us4*>(BsH + rbase + rd1);
            u.h[1] = *reinterpret_cast<const us4*>(BsH + rbase + rd2);
            bh[nb] = u.s;
            union { us4 h[2]; short8 s; } v;
            v.h[0] = *reinterpret_cast<const us4*>(BsL + rbase + rd1);
            v.h[1] = *reinterpret_cast<const us4*>(BsL + rbase + rd2);
            bl[nb] = v.s;
        }
#pragma unroll
        for (int mb = 0; mb < 4; ++mb) {
            const int rbase = (wr * 64 + mb * 16 + l15) * 32;
            union { us4 h[2]; short8 s; } ua;
            ua.h[0] = *reinterpret_cast<const us4*>(AsH + rbase + rd1);
            ua.h[1] = *reinterpret_cast<const us4*>(AsH + rbase + rd2);
            union { us4 h[2]; short8 s; } ul;
            ul.h[0] = *reinterpret_cast<const us4*>(AsL + rbase + rd1);
            ul.h[1] = *reinterpret_cast<const us4*>(AsL + rbase + rd2);
            const short8 ah = ua.s, al = ul.s;
#pragma unroll
            for (int nb = 0; nb < 4; ++nb) {
                acc[mb][nb] = __builtin_amdgcn_mfma_f32_16x16x32_bf16(ah, bh[nb], acc[mb][nb], 0, 0, 0);
                acc[mb][nb] = __builtin_amdgcn_mfma_f32_16x16x32_bf16(al, bh[nb], acc[mb][nb], 0, 0, 0);
                acc[mb][nb] = __builtin_amdgcn_mfma_f32_16x16x32_bf16(ah, bl[nb], acc[mb][nb], 0, 0, 0);
            }
        }
    }
}

// ---------------- fused QKV GEMM (bf16 out, alpha fold) ----------------
__global__ __launch_bounds__(256, 3)
void gemm_qkv(const ushort_t* __restrict__ xh, const ushort_t* __restrict__ xl,
              const ushort_t* __restrict__ Wth, const ushort_t* __restrict__ Wtl,
              const float* __restrict__ bq, const float* __restrict__ bk,
              const float* __restrict__ bv,
              ushort_t* __restrict__ Qb, ushort_t* __restrict__ Kb,
              ushort_t* __restrict__ Vb, float qalpha)
{
    __shared__ ushort_t AsH[128 * 32], AsL[128 * 32], BsH[128 * 32], BsL[128 * 32];
    const int which = blockIdx.x >> 3;
    const int n0 = (blockIdx.x & 7) * 128;
    const int m0 = blockIdx.y * 128;
    const ushort_t* Bh = Wth + (size_t)which * 1024 * 1024;
    const ushort_t* Bl = Wtl + (size_t)which * 1024 * 1024;
    const float* bias = (which == 0) ? bq : (which == 1) ? bk : bv;
    ushort_t* out = (which == 0) ? Qb : (which == 1) ? Kb : Vb;
    const float alpha = (which == 0) ? qalpha : 1.0f;

    f32x4 acc[4][4];
#pragma unroll
    for (int i = 0; i < 4; ++i)
#pragma unroll
        for (int j = 0; j < 4; ++j) { acc[i][j][0] = 0.f; acc[i][j][1] = 0.f; acc[i][j][2] = 0.f; acc[i][j][3] = 0.f; }

    gemm128_core(xh, xl, Bh, Bl, m0, n0, AsH, AsL, BsH, BsL, acc);

    const int tid = threadIdx.x;
    const int lane = tid & 63, l15 = lane & 15, g = lane >> 4;
    const int w = tid >> 6, wr = w >> 1, wc = w & 1;
    float bvv[4];
#pragma unroll
    for (int nb = 0; nb < 4; ++nb) bvv[nb] = bias[n0 + wc * 64 + nb * 16 + l15];
#pragma unroll
    for (int mb = 0; mb < 4; ++mb)
#pragma unroll
        for (int r = 0; r < 4; ++r) {
            const size_t row = m0 + wr * 64 + mb * 16 + 4 * g + r;
#pragma unroll
            for (int nb = 0; nb < 4; ++nb) {
                const float vv = (acc[mb][nb][r] + bvv[nb]) * alpha;
                out[row * 1024 + n0 + wc * 64 + nb * 16 + l15] = f2bf(vv);
            }
        }
}

// ---------------- output GEMM (fp32 out) ----------------
__global__ __launch_bounds__(256, 3)
void gemm_o(const ushort_t* __restrict__ Ah, const ushort_t* __restrict__ Al,
            const ushort_t* __restrict__ Bh, const ushort_t* __restrict__ Bl,
            const float* __restrict__ bias, float* __restrict__ out)
{
    __shared__ ushort_t AsH[128 * 32], AsL[128 * 32], BsH[128 * 32], BsL[128 * 32];
    const int n0 = blockIdx.x * 128;
    const int m0 = blockIdx.y * 128;

    f32x4 acc[4][4];
#pragma unroll
    for (int i = 0; i < 4; ++i)
#pragma unroll
        for (int j = 0; j < 4; ++j) { acc[i][j][0] = 0.f; acc[i][j][1] = 0.f; acc[i][j][2] = 0.f; acc[i][j][3] = 0.f; }

    gemm128_core(Ah, Al, Bh, Bl, m0, n0, AsH, AsL, BsH, BsL, acc);

    const int tid = threadIdx.x;
    const int lane = tid & 63, l15 = lane & 15, g = lane >> 4;
    const int w = tid >> 6, wr = w >> 1, wc = w & 1;
    float bvv[4];
#pragma unroll
    for (int nb = 0; nb < 4; ++nb) bvv[nb] = bias[n0 + wc * 64 + nb * 16 + l15];
#pragma unroll
    for (int mb = 0; mb < 4; ++mb)
#pragma unroll
        for (int r = 0; r < 4; ++r) {
            const size_t row = m0 + wr * 64 + mb * 16 + 4 * g + r;
#pragma unroll
            for (int nb = 0; nb < 4; ++nb)
                out[row * 1024 + n0 + wc * 64 + nb * 16 + l15] = acc[mb][nb][r] + bvv[nb];
        }
}

// ---------------- MFMA bf16 flash attention (round-2 verified core) ----------------
__global__ __launch_bounds__(256, 2)
void attn_mfma(const ushort_t* __restrict__ Q, const ushort_t* __restrict__ K,
               const ushort_t* __restrict__ V, ushort_t* __restrict__ XHh,
               ushort_t* __restrict__ XHl)
{
    __shared__ __align__(16) ushort_t Kf[4 * 2 * 64 * 8];
    __shared__ __align__(16) ushort_t Vf[4 * 2 * 64 * 8];

    const int tid  = threadIdx.x;
    const int w    = tid >> 6;
    const int lane = tid & 63;
    const int l15  = lane & 15;
    const int g    = lane >> 4;

    const int qb = blockIdx.x;
    const int bh = blockIdx.y;
    const int b  = bh >> 4;
    const int hh = bh & 15;
    const size_t hoff = (size_t)b * S_ * E_ + (size_t)hh * S_ * D_;
    const ushort_t* Qh = Q + hoff;
    const ushort_t* Kh = K + hoff;
    const ushort_t* Vh = V + hoff;

    const int qw = qb * 128 + w * 32;

    short8 qf[2][2];
#pragma unroll
    for (int qg = 0; qg < 2; ++qg)
#pragma unroll
        for (int m = 0; m < 2; ++m) {
            const ushort_t* src = &Qh[(size_t)(qw + 16 * qg + l15) * D_ + 32 * m + 4 * g];
            us4 lo = *reinterpret_cast<const us4*>(src);
            us4 hi = *reinterpret_cast<const us4*>(src + 16);
            union { us4 h[2]; short8 s; } u;
            u.h[0] = lo; u.h[1] = hi;
            qf[qg][m] = u.s;
        }

    const int kr  = tid >> 2;
    const int kc0 = tid & 3;
    const int kkc = tid >> 4;
    const int vdc = tid & 15;
    const int vmc = kkc >> 3;
    const int vh  = (kkc >> 2) & 1;
    const int vg  = kkc & 3;
    const int vn  = vdc >> 2;

    f32x4 o[2][4];
#pragma unroll
    for (int qg = 0; qg < 2; ++qg)
#pragma unroll
        for (int n = 0; n < 4; ++n)
#pragma unroll
            for (int r = 0; r < 4; ++r) o[qg][n][r] = 0.f;

    float mrun[2] = {-1e30f, -1e30f};
    float lrun[2] = {0.f, 0.f};

    for (int kt = 0; kt < S_ / 64; ++kt) {
        us8 kreg[2];
#pragma unroll
        for (int u = 0; u < 2; ++u) {
            const int c8 = kc0 + 4 * u;
            kreg[u] = *reinterpret_cast<const us8*>(&Kh[(size_t)(kt * 64 + kr) * D_ + 8 * c8]);
        }
        us4 vreg[4];
#pragma unroll
        for (int i = 0; i < 4; ++i)
            vreg[i] = *reinterpret_cast<const us4*>(&Vh[(size_t)(kt * 64 + 4 * kkc + i) * D_ + 4 * vdc]);

        __syncthreads();

#pragma unroll
        for (int u = 0; u < 2; ++u) {
            const int c8 = kc0 + 4 * u;
            const int m = c8 >> 2;
            const int h = (c8 >> 1) & 1;
#pragma unroll
            for (int jh = 0; jh < 2; ++jh) {
                const int gk = (2 * c8 + jh) & 3;
                const int slot = gk * 16 + (kr & 15);
                us4 val;
#pragma unroll
                for (int i = 0; i < 4; ++i) val[i] = (ushort_t)kreg[u][4 * jh + i];
                *reinterpret_cast<us4*>(&Kf[((((kr >> 4) * 2 + m) * 64 + slot) * 8) + h * 4]) = val;
            }
        }
#pragma unroll
        for (int jj = 0; jj < 4; ++jj) {
            us4 val;
#pragma unroll
            for (int i = 0; i < 4; ++i) val[i] = vreg[i][jj];
            const int slot = vg * 16 + 4 * (vdc & 3) + jj;
            *reinterpret_cast<us4*>(&Vf[(((vn * 2 + vmc) * 64 + slot) * 8) + vh * 4]) = val;
        }
        __syncthreads();

        short8 kf[4][2];
#pragma unroll
        for (int kkb = 0; kkb < 4; ++kkb)
#pragma unroll
            for (int m = 0; m < 2; ++m)
                kf[kkb][m] = *reinterpret_cast<const short8*>(&Kf[((kkb * 2 + m) * 64 + lane) * 8]);

        f32x4 s[2][4];
#pragma unroll
        for (int qg = 0; qg < 2; ++qg)
#pragma unroll
            for (int kkb = 0; kkb < 4; ++kkb) {
                f32x4 z; z[0] = 0.f; z[1] = 0.f; z[2] = 0.f; z[3] = 0.f;
                z = __builtin_amdgcn_mfma_f32_16x16x32_bf16(kf[kkb][0], qf[qg][0], z, 0, 0, 0);
                s[qg][kkb] = __builtin_amdgcn_mfma_f32_16x16x32_bf16(kf[kkb][1], qf[qg][1], z, 0, 0, 0);
            }

        short8 vf[4][2];
#pragma unroll
        for (int n = 0; n < 4; ++n)
#pragma unroll
            for (int m = 0; m < 2; ++m)
                vf[n][m] = *reinterpret_cast<const short8*>(&Vf[((n * 2 + m) * 64 + lane) * 8]);

#pragma unroll
        for (int qg = 0; qg < 2; ++qg) {
            float t = s[qg][0][0];
#pragma unroll
            for (int kkb = 0; kkb < 4; ++kkb)
#pragma unroll
                for (int r = 0; r < 4; ++r) t = fmaxf(t, s[qg][kkb][r]);
            t = fmaxf(t, __shfl_xor(t, 16));
            t = fmaxf(t, __shfl_xor(t, 32));
            const float mnew = fmaxf(mrun[qg], t);
            const float corr = __builtin_amdgcn_exp2f(mrun[qg] - mnew);

            float rs = 0.f;
#pragma unroll
            for (int kkb = 0; kkb < 4; ++kkb)
#pragma unroll
                for (int r = 0; r < 4; ++r) {
                    const float p = __builtin_amdgcn_exp2f(s[qg][kkb][r] - mnew);
                    s[qg][kkb][r] = p;
                    rs += p;
                }
            rs += __shfl_xor(rs, 16);
            rs += __shfl_xor(rs, 32);
            lrun[qg] = lrun[qg] * corr + rs;
            mrun[qg] = mnew;

#pragma unroll
            for (int r = 0; r < 4; ++r) {
                const float c4 = __shfl(corr, 4 * g + r);
#pragma unroll
                for (int n = 0; n < 4; ++n) o[qg][n][r] *= c4;
            }

            short8 pa[2];
#pragma unroll
            for (int m = 0; m < 2; ++m) {
                us8 tmp;
#pragma unroll
                for (int r = 0; r < 4; ++r) {
                    tmp[r]     = f2bf(s[qg][2 * m][r]);
                    tmp[r + 4] = f2bf(s[qg][2 * m + 1][r]);
                }
                union { us8 u8; short8 s8; } cvt; cvt.u8 = tmp;
                pa[m] = cvt.s8;
            }
#pragma unroll
            for (int n = 0; n < 4; ++n) {
                o[qg][n] = __builtin_amdgcn_mfma_f32_16x16x32_bf16(pa[0], vf[n][0], o[qg][n], 0, 0, 0);
                o[qg][n] = __builtin_amdgcn_mfma_f32_16x16x32_bf16(pa[1], vf[n][1], o[qg][n], 0, 0, 0);
            }
        }
    }

    // epilogue: divide by l, write hi/lo bf16 XH[b][s][hh*64+d]
#pragma unroll
    for (int qg = 0; qg < 2; ++qg) {
        const float invl = 1.f / lrun[qg];
#pragma unroll
        for (int r = 0; r < 4; ++r) {
            const float iv = __shfl(invl, 4 * g + r);
            const int row = qw + 16 * qg + 4 * g + r;
            const size_t base = ((size_t)b * S_ + row) * E_ + hh * D_ + l15;
#pragma unroll
            for (int n = 0; n < 4; ++n) {
                const float vv = o[qg][n][r] * iv;
                const ushort_t hi = f2bf(vv);
                XHh[base + 16 * n] = hi;
                XHl[base + 16 * n] = f2bf(vv - bf2f(hi));
            }
        }
    }
}

extern "C" void kernel_launch(void* const* d_in, const int* in_sizes, int n_in,
                              void* d_out, int out_size, void* d_ws, size_t ws_size,
                              hipStream_t stream) {
    (void)in_sizes; (void)n_in; (void)out_size; (void)ws_size;
    const float* x  = (const float*)d_in[0];
    const float* Wq = (const float*)d_in[1];
    const float* bq = (const float*)d_in[2];
    const float* Wk = (const float*)d_in[3];
    const float* bk = (const float*)d_in[4];
    const float* Wv = (const float*)d_in[5];
    const float* bv = (const float*)d_in[6];
    const float* Wo = (const float*)d_in[7];
    const float* bo = (const float*)d_in[8];
    float* out = (float*)d_out;

    char* ws = (char*)d_ws;
    const size_t MB8 = 8ull * 1024 * 1024;
    ushort_t* xhi = (ushort_t*)(ws);             // 8 MB, reused as XHh after QKV
    ushort_t* xlo = (ushort_t*)(ws + MB8);       // 8 MB, reused as XHl
    ushort_t* Wth = (ushort_t*)(ws + 2 * MB8);   // 8 MB  [4][1024][1024]
    ushort_t* Wtl = (ushort_t*)(ws + 3 * MB8);   // 8 MB
    ushort_t* Qb  = (ushort_t*)(ws + 4 * MB8);   // 8 MB
    ushort_t* Kb  = (ushort_t*)(ws + 5 * MB8);   // 8 MB
    ushort_t* Vb  = (ushort_t*)(ws + 6 * MB8);   // 8 MB  (total 56 MB)
    ushort_t* XHh = xhi;
    ushort_t* XHl = xlo;

    const float qalpha = 0.125f * 1.4426950408889634f;  // 1/sqrt(D) * log2(e)

    split_x<<<dim3(2048), dim3(256), 0, stream>>>(x, xhi, xlo);
    wsplit_t<<<dim3(16, 16, 4), dim3(256), 0, stream>>>(Wq, Wk, Wv, Wo, Wth, Wtl);

    gemm_qkv<<<dim3(24, 32), dim3(256), 0, stream>>>(xhi, xlo, Wth, Wtl,
                                                     bq, bk, bv, Qb, Kb, Vb, qalpha);

    attn_mfma<<<dim3(16, 32), dim3(256), 0, stream>>>(Qb, Kb, Vb, XHh, XHl);

    gemm_o<<<dim3(8, 32), dim3(256), 0, stream>>>(XHh, XHl,
                                                  Wth + 3ull * 1024 * 1024,
                                                  Wtl + 3ull * 1024 * 1024,
                                                  bo, out);
}